// Round 9
// baseline (548.844 us; speedup 1.0000x reference)
//
#include <hip/hip_runtime.h>
#include <stdint.h>

#define N_PTS 262144
#define CDIM 128
#define BDIM 8
#define HID 256
#define TW 128
#define MAXB 2056
#define SCALE_F 0.17677669529663687f
#define LN_EPS 1e-5f

typedef unsigned short u16;
typedef __attribute__((ext_vector_type(8))) short short8v;
typedef __attribute__((ext_vector_type(4))) float f32x4;
typedef __attribute__((ext_vector_type(8))) float f32x8;

__device__ __forceinline__ u16 f2bf(float f){
  union { float f; uint32_t u; } v; v.f = f;
  uint32_t r = v.u + 0x7fffu + ((v.u>>16)&1u);
  return (u16)(r>>16);
}
__device__ __forceinline__ float bf2f(u16 u){
  union { uint32_t u; float f; } v; v.u = ((uint32_t)u)<<16; return v.f;
}

// ---------------- bucket id + histogram ----------------
__global__ __launch_bounds__(256) void k_bucket(const int* __restrict__ batch,
                                                const int* __restrict__ lengths,
                                                const float* __restrict__ scores,
                                                int* __restrict__ gb, int* __restrict__ hist){
  int i = blockIdx.x*256 + threadIdx.x;
  if(i >= N_PTS) return;
  int b = batch[i];
  int boff = 0, nb = 1;
  #pragma unroll
  for(int j=0;j<BDIM;j++){
    int nbj = (lengths[j] + TW - 1)/TW;
    if(j <  b) boff += nbj;
    if(j == b) nb = nbj;
  }
  float sc = scores[i];
  int local = (int)(sc * (float)nb);
  if(local > nb-1) local = nb-1;
  if(local < 0) local = 0;
  int g = local + boff;
  gb[i] = g;
  atomicAdd(&hist[g], 1);
}

// ---------------- exclusive scan over MAXB histogram ----------------
__global__ __launch_bounds__(256) void k_scan(const int* __restrict__ hist,
                                              int* __restrict__ start, int* __restrict__ cursor){
  __shared__ int ssum[256];
  const int t = threadIdx.x;
  const int CH = 9;              // 256*9 = 2304 >= 2056
  int loc[CH];
  int s = 0;
  #pragma unroll
  for(int i=0;i<CH;i++){
    int idx = t*CH + i;
    int v = (idx < MAXB) ? hist[idx] : 0;
    loc[i] = s; s += v;
  }
  ssum[t] = s; __syncthreads();
  for(int off=1; off<256; off<<=1){
    int v = (t>=off)? ssum[t-off] : 0;
    __syncthreads();
    ssum[t] += v;
    __syncthreads();
  }
  int ex = ssum[t] - s;          // exclusive prefix of this chunk
  #pragma unroll
  for(int i=0;i<CH;i++){
    int idx = t*CH + i;
    if(idx < MAXB){ int st = ex + loc[i]; start[idx] = st; cursor[idx] = st; }
  }
}

// ---------------- counting-sort scatter ----------------
__global__ __launch_bounds__(256) void k_scatter(const int* __restrict__ gb,
                                                 int* __restrict__ cursor, int* __restrict__ sidx){
  int i = blockIdx.x*256 + threadIdx.x;
  if(i >= N_PTS) return;
  int pos = atomicAdd(&cursor[gb[i]], 1);
  sidx[pos] = i;
}

// ---------------- per-bucket centroid of LN1(feat), load-ahead pipelined ----------------
__global__ __launch_bounds__(256) void k_centroid(const float* __restrict__ feat,
                                                  const int* __restrict__ sidx,
                                                  const int* __restrict__ start,
                                                  const int* __restrict__ hist,
                                                  const float* __restrict__ g1, const float* __restrict__ b1,
                                                  float* __restrict__ cent){
  const int b = blockIdx.x;
  const int cnt = hist[b], st = start[b];
  const int tid = threadIdx.x;
  const int w = tid>>6, lane = tid&63;
  const int c0 = lane*2;
  float g1a = g1[c0], g1b = g1[c0+1];
  float b1a = b1[c0], b1b = b1[c0+1];
  float a0 = 0.f, a1 = 0.f;
  float nx0 = 0.f, nx1 = 0.f;
  int i = w;
  if(i < cnt){
    int p = sidx[st+i];
    const float* fp = feat + (size_t)p*CDIM + c0;
    nx0 = fp[0]; nx1 = fp[1];
  }
  for(; i < cnt; ){
    float x0 = nx0, x1 = nx1;
    int ni = i + 4;
    if(ni < cnt){                                   // prefetch next point under the reduce
      int np = sidx[st+ni];
      const float* fp = feat + (size_t)np*CDIM + c0;
      nx0 = fp[0]; nx1 = fp[1];
    }
    float s = x0+x1, sq = x0*x0 + x1*x1;
    #pragma unroll
    for(int m=1;m<64;m<<=1){ s += __shfl_xor(s,m,64); sq += __shfl_xor(sq,m,64); }
    float mu = s*(1.f/128.f);
    float var = sq*(1.f/128.f) - mu*mu;
    float rs = rsqrtf(var + LN_EPS);
    a0 += (x0-mu)*rs*g1a + b1a;
    a1 += (x1-mu)*rs*g1b + b1b;
    i = ni;
  }
  __shared__ float red[4][128];
  red[w][c0] = a0; red[w][c0+1] = a1;
  __syncthreads();
  if(tid < 128){
    float t = red[0][tid] + red[1][tid] + red[2][tid] + red[3][tid];
    float cf = (float)(cnt > 0 ? cnt : 1);
    cent[(size_t)b*CDIM + tid] = t / cf;
  }
}

// ---------------- centroid projections kc = cent@Wk+bk, vc = cent@Wv+bv ----------------
__global__ __launch_bounds__(128) void k_cgemm(const float* __restrict__ cent,
                                               const float* __restrict__ Wk, const float* __restrict__ bk,
                                               const float* __restrict__ Wv, const float* __restrict__ bv,
                                               float* __restrict__ kc, float* __restrict__ vc){
  const int b = blockIdx.x, t = threadIdx.x;
  __shared__ float sc[128];
  sc[t] = cent[(size_t)b*CDIM + t];
  __syncthreads();
  float ak = bk[t], av = bv[t];
  for(int d=0; d<CDIM; ++d){
    float c = sc[d];
    ak += c * Wk[d*CDIM + t];
    av += c * Wv[d*CDIM + t];
  }
  kc[(size_t)b*CDIM + t] = ak;
  vc[(size_t)b*CDIM + t] = av;
}

// ---------------- pack all 5 fp32 weights into bf16 per-MFMA-B-fragment layout ----------------
__device__ __forceinline__ void pack_one(const float* __restrict__ W, u16* __restrict__ dst,
                                         int NC, int idx){
  int e = idx & 7;
  int l = (idx>>3) & 63;
  int f = idx >> 9;
  int nCT = NC >> 4;
  int cT = f % nCT, kT = f / nCT;
  int k = kT*32 + (l>>4)*8 + e;
  int c = cT*16 + (l&15);
  dst[idx] = f2bf(W[k*NC + c]);
}
__global__ __launch_bounds__(256) void k_packall(const float* __restrict__ Wq, u16* __restrict__ pWq,
                                                 const float* __restrict__ Wg, u16* __restrict__ pWg,
                                                 const float* __restrict__ Wp, u16* __restrict__ pWp,
                                                 const float* __restrict__ W1, u16* __restrict__ pW1,
                                                 const float* __restrict__ W2, u16* __restrict__ pW2){
  int idx = blockIdx.x*256 + threadIdx.x;
  if(idx < 16384){ pack_one(Wq, pWq, CDIM, idx); return; }
  idx -= 16384;
  if(idx < 16384){ pack_one(Wg, pWg, CDIM, idx); return; }
  idx -= 16384;
  if(idx < 16384){ pack_one(Wp, pWp, CDIM, idx); return; }
  idx -= 16384;
  if(idx < 32768){ pack_one(W1, pW1, HID, idx); return; }
  idx -= 32768;
  if(idx < 32768){ pack_one(W2, pW2, CDIM, idx); }
}

// ---------------- fully fused block ----------------
// All LDS traffic is warp-private 16-row slabs -> no __syncthreads.
// R4-R8 lesson: the allocator targets a 64-84 VGPR budget for this kernel no
// matter what attributes say, and SPILLS anything bigger (~0.9-1.7 GB scratch).
// So make true peak pressure fit ~64: every GEMM phase uses acc4[4] (16 VGPR)
// and processes output columns in 4-cT groups; Phase D re-reads out[] for the
// LN2 pass instead of keeping x1v[8] live. No waves_per_eu attr (R8's max=3
// clamp capped occupancy at 12 waves/CU while not stopping the spill).
__global__ __attribute__((amdgpu_flat_work_group_size(256, 256)))
void k_fused(const float* __restrict__ feat,
             const int* __restrict__ gb,
             const float* __restrict__ kc, const float* __restrict__ vc,
             const u16* __restrict__ pWq, const u16* __restrict__ pWg,
             const u16* __restrict__ pWp,
             const u16* __restrict__ pW1, const u16* __restrict__ pW2,
             const float* __restrict__ bq, const float* __restrict__ bg,
             const float* __restrict__ bp,
             const float* __restrict__ g1, const float* __restrict__ b1,
             const float* __restrict__ g2, const float* __restrict__ b2,
             const float* __restrict__ bias1, const float* __restrict__ gam_f,
             const float* __restrict__ bet_f, const float* __restrict__ bias2,
             float* __restrict__ out){
  // Buffer A: LN1(x) -> gate -> t[cols 0..127]
  // Buffer Q: q -> LN2(x1) -> t[cols 128..255]
  __shared__ __align__(16) u16 bufA[64*128];
  __shared__ __align__(16) u16 bufQ[64*128];
  char* A8 = (char*)bufA;
  char* Q8 = (char*)bufQ;
  const int tid = threadIdx.x;
  const int wid = tid>>6, lane = tid&63;
  const int row0 = blockIdx.x*64;

  // ---- Phase A: stage LN1(feat) into bufA (swizzled bf16) ----
  {
    const int cb = (lane&15)*16;
    const f32x8 gv  = *(const f32x8*)(g1 + (lane&15)*8);
    const f32x8 bv8 = *(const f32x8*)(b1 + (lane&15)*8);
    #pragma unroll
    for(int it=0; it<4; ++it){
      int rl = wid*16 + it*4 + (lane>>4);
      const f32x8 f8 = *(const f32x8*)(feat + (size_t)(row0+rl)*CDIM + (lane&15)*8);
      float s=0.f, sq=0.f;
      #pragma unroll
      for(int e=0;e<8;e++){ s += f8[e]; sq += f8[e]*f8[e]; }
      #pragma unroll
      for(int m=1;m<16;m<<=1){ s += __shfl_xor(s,m,64); sq += __shfl_xor(sq,m,64); }
      float mu = s*(1.f/128.f);
      float var = sq*(1.f/128.f) - mu*mu;
      float rs = rsqrtf(var + LN_EPS);
      short8v h;
      #pragma unroll
      for(int e=0;e<8;e++){
        float x = (f8[e]-mu)*rs*gv[e] + bv8[e];
        h[e] = (short)f2bf(x);
      }
      *(short8v*)(A8 + rl*256 + (cb ^ ((rl&7)<<4))) = h;
    }
  }
  __builtin_amdgcn_sched_barrier(0);

  const int arow = wid*16 + (lane&15);
  const int kgrp = (lane>>4);

  short8v af[4];
  f32x4 acc4[4];

  // ---- Phase B: q = x_ln @ Wq + bq -> bufQ (two 4-cT halves) ----
  #pragma unroll
  for(int kT=0;kT<4;kT++)
    af[kT] = *(const short8v*)(A8 + arow*256 + (((kT*64) + kgrp*16) ^ ((arow&7)<<4)));
  #pragma unroll
  for(int h=0;h<2;h++){
    #pragma unroll
    for(int c4=0;c4<4;c4++){
      int cT = h*4 + c4;
      f32x4 a = {0.f,0.f,0.f,0.f};
      #pragma unroll
      for(int kT=0;kT<4;kT++){
        const short8v b8 = *(const short8v*)(pWq + ((size_t)((kT*8+cT)*64 + lane)*8));
        a = __builtin_amdgcn_mfma_f32_16x16x32_bf16(af[kT], b8, a, 0,0,0);
      }
      acc4[c4] = a;
    }
    #pragma unroll
    for(int c4=0;c4<4;c4++){
      int col = (h*4+c4)*16 + (lane&15);
      float bqv = bq[col];
      #pragma unroll
      for(int r=0;r<4;r++){
        int rl = wid*16 + kgrp*4 + r;
        *(u16*)(Q8 + rl*256 + ((col*2) ^ ((rl&7)<<4))) = f2bf(acc4[c4][r] + bqv);
      }
    }
  }
  __builtin_amdgcn_sched_barrier(0);

  const int myb = gb[row0 + arow];

  // ---- Phase C: gate = sigmoid((q*kc*SCALE) @ Wg + bg) -> bufA ----
  #pragma unroll
  for(int kT=0;kT<4;kT++){
    const short8v q8 = *(const short8v*)(Q8 + arow*256 + (((kT*64) + kgrp*16) ^ ((arow&7)<<4)));
    const f32x4 ka = *(const f32x4*)(kc + (size_t)myb*CDIM + kT*32 + kgrp*8);
    const f32x4 kb = *(const f32x4*)(kc + (size_t)myb*CDIM + kT*32 + kgrp*8 + 4);
    short8v a;
    #pragma unroll
    for(int e=0;e<4;e++) a[e]   = (short)f2bf(bf2f((u16)q8[e])   * ka[e] * SCALE_F);
    #pragma unroll
    for(int e=0;e<4;e++) a[e+4] = (short)f2bf(bf2f((u16)q8[e+4]) * kb[e] * SCALE_F);
    af[kT] = a;
  }
  #pragma unroll
  for(int h=0;h<2;h++){
    #pragma unroll
    for(int c4=0;c4<4;c4++){
      int cT = h*4 + c4;
      f32x4 a = {0.f,0.f,0.f,0.f};
      #pragma unroll
      for(int kT=0;kT<4;kT++){
        const short8v b8 = *(const short8v*)(pWg + ((size_t)((kT*8+cT)*64 + lane)*8));
        a = __builtin_amdgcn_mfma_f32_16x16x32_bf16(af[kT], b8, a, 0,0,0);
      }
      acc4[c4] = a;
    }
    #pragma unroll
    for(int c4=0;c4<4;c4++){
      int col = (h*4+c4)*16 + (lane&15);
      float bgv = bg[col];
      #pragma unroll
      for(int r=0;r<4;r++){
        int rl = wid*16 + kgrp*4 + r;
        float x = acc4[c4][r] + bgv;
        float sg = 1.f/(1.f + __expf(-x));
        *(u16*)(A8 + rl*256 + ((col*2) ^ ((rl&7)<<4))) = f2bf(sg);
      }
    }
  }
  __builtin_amdgcn_sched_barrier(0);

  // ---- Phase D: x_out = (gate*vc) @ Wp + bp ; x1 = feat + x_out -> out (fp32);
  //      LN2 stats accumulated per half; LN2(x1) -> bufQ via out re-read ----
  #pragma unroll
  for(int kT=0;kT<4;kT++){
    const short8v q8 = *(const short8v*)(A8 + arow*256 + (((kT*64) + kgrp*16) ^ ((arow&7)<<4)));
    const f32x4 va = *(const f32x4*)(vc + (size_t)myb*CDIM + kT*32 + kgrp*8);
    const f32x4 vb = *(const f32x4*)(vc + (size_t)myb*CDIM + kT*32 + kgrp*8 + 4);
    short8v a;
    #pragma unroll
    for(int e=0;e<4;e++) a[e]   = (short)f2bf(bf2f((u16)q8[e])   * va[e]);
    #pragma unroll
    for(int e=0;e<4;e++) a[e+4] = (short)f2bf(bf2f((u16)q8[e+4]) * vb[e]);
    af[kT] = a;
  }
  float sD[4]  = {0.f,0.f,0.f,0.f};
  float sqD[4] = {0.f,0.f,0.f,0.f};
  #pragma unroll
  for(int h=0;h<2;h++){
    #pragma unroll
    for(int c4=0;c4<4;c4++){
      int cT = h*4 + c4;
      f32x4 a = {0.f,0.f,0.f,0.f};
      #pragma unroll
      for(int kT=0;kT<4;kT++){
        const short8v b8 = *(const short8v*)(pWp + ((size_t)((kT*8+cT)*64 + lane)*8));
        a = __builtin_amdgcn_mfma_f32_16x16x32_bf16(af[kT], b8, a, 0,0,0);
      }
      acc4[c4] = a;
    }
    #pragma unroll
    for(int c4=0;c4<4;c4++){
      int col = (h*4+c4)*16 + (lane&15);
      float bpv = bp[col];
      #pragma unroll
      for(int r=0;r<4;r++){
        int rl = wid*16 + kgrp*4 + r;
        size_t gi = (size_t)(row0+rl)*CDIM + col;
        float x1 = feat[gi] + acc4[c4][r] + bpv;
        out[gi] = x1;                    // stash x1 (same thread re-reads below and in F)
        sD[r] += x1; sqD[r] += x1*x1;
      }
    }
  }
  {
    float muD[4], rsD[4];
    #pragma unroll
    for(int r=0;r<4;r++){
      float s = sD[r], sq = sqD[r];
      #pragma unroll
      for(int m=1;m<16;m<<=1){ s += __shfl_xor(s,m,64); sq += __shfl_xor(sq,m,64); }
      float mu = s*(1.f/128.f);
      float var = sq*(1.f/128.f) - mu*mu;
      muD[r] = mu; rsD[r] = rsqrtf(var + LN_EPS);
    }
    #pragma unroll
    for(int cT=0;cT<8;cT++){
      int col = cT*16 + (lane&15);
      float gm = g2[col], bt = b2[col];
      #pragma unroll
      for(int r=0;r<4;r++){
        int rl = wid*16 + kgrp*4 + r;
        size_t gi = (size_t)(row0+rl)*CDIM + col;
        float ln = (out[gi]-muD[r])*rsD[r]*gm + bt;
        *(u16*)(Q8 + rl*256 + ((col*2) ^ ((rl&7)<<4))) = f2bf(ln);
      }
    }
  }
  __builtin_amdgcn_sched_barrier(0);

  // ---- Phase E: h = LN2(x1) @ Wf1 + bf1, four 4-cT quarters (acc4 cap);
  //      h staged bf16 into bufA (lo cols) / bufQ (hi cols), LN sums in f32;
  //      then in-place innerLN+ReLU RMW -> t ----
  #pragma unroll
  for(int kT=0;kT<4;kT++)
    af[kT] = *(const short8v*)(Q8 + arow*256 + (((kT*64) + kgrp*16) ^ ((arow&7)<<4)));
  float sE[4]  = {0.f,0.f,0.f,0.f};
  float sqE[4] = {0.f,0.f,0.f,0.f};
  #pragma unroll
  for(int q=0;q<4;q++){
    #pragma unroll
    for(int c4=0;c4<4;c4++){
      int cT = q*4 + c4;
      f32x4 a = {0.f,0.f,0.f,0.f};
      #pragma unroll
      for(int kT=0;kT<4;kT++){
        const short8v b8 = *(const short8v*)(pW1 + ((size_t)((kT*16+cT)*64 + lane)*8));
        a = __builtin_amdgcn_mfma_f32_16x16x32_bf16(af[kT], b8, a, 0,0,0);
      }
      acc4[c4] = a;
    }
    #pragma unroll
    for(int c4=0;c4<4;c4++){
      int cT = q*4 + c4;
      int col = cT*16 + (lane&15);
      float bv = bias1[col];
      char* base = (cT<8) ? A8 : Q8;
      int cb = (cT<8) ? col*2 : (col-128)*2;
      #pragma unroll
      for(int r=0;r<4;r++){
        int rl = wid*16 + kgrp*4 + r;
        float v = acc4[c4][r] + bv;
        sE[r] += v; sqE[r] += v*v;
        *(u16*)(base + rl*256 + (cb ^ ((rl&7)<<4))) = f2bf(v);
      }
    }
  }
  {
    float muE[4], rsE[4];
    #pragma unroll
    for(int r=0;r<4;r++){
      float s = sE[r], sq = sqE[r];
      #pragma unroll
      for(int m=1;m<16;m<<=1){ s += __shfl_xor(s,m,64); sq += __shfl_xor(sq,m,64); }
      float mu = s*(1.f/256.f);
      float var = sq*(1.f/256.f) - mu*mu;
      muE[r] = mu; rsE[r] = rsqrtf(var + LN_EPS);
    }
    // in-place LN+ReLU RMW (warp-private rows; gamma/beta hoisted per cT)
    #pragma unroll
    for(int cT=0;cT<16;cT++){
      int col = cT*16 + (lane&15);
      float gm = gam_f[col], bt = bet_f[col];
      char* base = (cT<8) ? A8 : Q8;
      int cb = (cT<8) ? col*2 : (col-128)*2;
      #pragma unroll
      for(int r=0;r<4;r++){
        int rl = wid*16 + kgrp*4 + r;
        u16* p = (u16*)(base + rl*256 + (cb ^ ((rl&7)<<4)));
        float hh = bf2f(*p);
        float t = (hh - muE[r])*rsE[r]*gm + bt;
        *p = f2bf(fmaxf(t, 0.f));
      }
    }
  }
  __builtin_amdgcn_sched_barrier(0);

  // ---- Phase F: out = x1 + t @ Wf2 + bf2 (two 4-cT halves; af reloaded per half) ----
  #pragma unroll
  for(int h=0;h<2;h++){
    #pragma unroll
    for(int c4=0;c4<4;c4++) acc4[c4] = (f32x4){0.f,0.f,0.f,0.f};
    #pragma unroll
    for(int kT=0;kT<4;kT++)
      af[kT] = *(const short8v*)(A8 + arow*256 + (((kT*64) + kgrp*16) ^ ((arow&7)<<4)));
    #pragma unroll
    for(int c4=0;c4<4;c4++){
      int cT = h*4 + c4;
      #pragma unroll
      for(int kT=0;kT<4;kT++){
        const short8v b8 = *(const short8v*)(pW2 + ((size_t)((kT*8+cT)*64 + lane)*8));
        acc4[c4] = __builtin_amdgcn_mfma_f32_16x16x32_bf16(af[kT], b8, acc4[c4], 0,0,0);
      }
    }
    #pragma unroll
    for(int kT=0;kT<4;kT++)
      af[kT] = *(const short8v*)(Q8 + arow*256 + (((kT*64) + kgrp*16) ^ ((arow&7)<<4)));
    #pragma unroll
    for(int c4=0;c4<4;c4++){
      int cT = h*4 + c4;
      #pragma unroll
      for(int kT=0;kT<4;kT++){
        const short8v b8 = *(const short8v*)(pW2 + ((size_t)(((kT+4)*8+cT)*64 + lane)*8));
        acc4[c4] = __builtin_amdgcn_mfma_f32_16x16x32_bf16(af[kT], b8, acc4[c4], 0,0,0);
      }
    }
    #pragma unroll
    for(int c4=0;c4<4;c4++){
      int col = (h*4+c4)*16 + (lane&15);
      float bv = bias2[col];
      #pragma unroll
      for(int r=0;r<4;r++){
        int rl = wid*16 + kgrp*4 + r;
        size_t gi = (size_t)(row0+rl)*CDIM + col;
        out[gi] = out[gi] + acc4[c4][r] + bv;   // out holds x1 (written by this thread)
      }
    }
  }
}

// ---------------- host ----------------
extern "C" void kernel_launch(void* const* d_in, const int* in_sizes, int n_in,
                              void* d_out, int out_size, void* d_ws, size_t ws_size,
                              hipStream_t stream){
  const float* feat    = (const float*)d_in[0];
  const int*   batch   = (const int*)d_in[1];
  const int*   lengths = (const int*)d_in[2];
  const float* scores  = (const float*)d_in[3];
  const float* Wq = (const float*)d_in[4];   const float* bq = (const float*)d_in[5];
  const float* Wk = (const float*)d_in[6];   const float* bk = (const float*)d_in[7];
  const float* Wv = (const float*)d_in[8];   const float* bv = (const float*)d_in[9];
  const float* Wg = (const float*)d_in[10];  const float* bg = (const float*)d_in[11];
  const float* Wp = (const float*)d_in[12];  const float* bp = (const float*)d_in[13];
  const float* g1 = (const float*)d_in[14];  const float* b1 = (const float*)d_in[15];
  const float* g2 = (const float*)d_in[16];  const float* b2 = (const float*)d_in[17];
  const float* Wf1 = (const float*)d_in[18]; const float* bf1 = (const float*)d_in[19];
  const float* gf  = (const float*)d_in[20]; const float* bfb = (const float*)d_in[21];
  const float* Wf2 = (const float*)d_in[22]; const float* bf2b = (const float*)d_in[23];

  char* ws = (char*)d_ws;
  size_t off = 0;
  auto alloc = [&](size_t bytes)->void*{
    void* p = ws + off;
    off = (off + bytes + 255) & ~(size_t)255;
    return p;
  };
  int*  gb     = (int*)alloc((size_t)N_PTS*4);
  int*  hist   = (int*)alloc((size_t)MAXB*4);
  int*  start  = (int*)alloc((size_t)MAXB*4);
  int*  cursor = (int*)alloc((size_t)MAXB*4);
  int*  sidx   = (int*)alloc((size_t)N_PTS*4);
  float* cent  = (float*)alloc((size_t)MAXB*CDIM*4);
  float* kc    = (float*)alloc((size_t)MAXB*CDIM*4);
  float* vc    = (float*)alloc((size_t)MAXB*CDIM*4);
  u16* pWq = (u16*)alloc((size_t)CDIM*CDIM*2);
  u16* pWg = (u16*)alloc((size_t)CDIM*CDIM*2);
  u16* pWp = (u16*)alloc((size_t)CDIM*CDIM*2);
  u16* pW1 = (u16*)alloc((size_t)CDIM*HID*2);
  u16* pW2 = (u16*)alloc((size_t)HID*CDIM*2);

  hipMemsetAsync(hist, 0, (size_t)MAXB*4, stream);

  k_bucket<<<N_PTS/256, 256, 0, stream>>>(batch, lengths, scores, gb, hist);
  k_scan<<<1, 256, 0, stream>>>(hist, start, cursor);
  k_scatter<<<N_PTS/256, 256, 0, stream>>>(gb, cursor, sidx);
  k_centroid<<<MAXB, 256, 0, stream>>>(feat, sidx, start, hist, g1, b1, cent);
  k_cgemm<<<MAXB, 128, 0, stream>>>(cent, Wk, bk, Wv, bv, kc, vc);
  k_packall<<<(114688+255)/256, 256, 0, stream>>>(Wq, pWq, Wg, pWg, Wp, pWp, Wf1, pW1, Wf2, pW2);

  k_fused<<<N_PTS/64, 256, 0, stream>>>(feat, gb, kc, vc, pWq, pWg, pWp, pW1, pW2,
                                        bq, bg, bp, g1, b1, g2, b2,
                                        bf1, gf, bfb, bf2b, (float*)d_out);
}

// Round 10
// 426.719 us; speedup vs baseline: 1.2862x; 1.2862x over previous
//
#include <hip/hip_runtime.h>
#include <stdint.h>

#define N_PTS 262144
#define CDIM 128
#define BDIM 8
#define HID 256
#define TW 128
#define MAXB 2056
#define SCALE_F 0.17677669529663687f
#define LN_EPS 1e-5f

typedef unsigned short u16;
typedef __attribute__((ext_vector_type(8))) short short8v;
typedef __attribute__((ext_vector_type(4))) float f32x4;
typedef __attribute__((ext_vector_type(8))) float f32x8;

__device__ __forceinline__ u16 f2bf(float f){
  union { float f; uint32_t u; } v; v.f = f;
  uint32_t r = v.u + 0x7fffu + ((v.u>>16)&1u);
  return (u16)(r>>16);
}
__device__ __forceinline__ float bf2f(u16 u){
  union { uint32_t u; float f; } v; v.u = ((uint32_t)u)<<16; return v.f;
}

// ---------------- bucket id + histogram ----------------
__global__ __launch_bounds__(256) void k_bucket(const int* __restrict__ batch,
                                                const int* __restrict__ lengths,
                                                const float* __restrict__ scores,
                                                int* __restrict__ gb, int* __restrict__ hist){
  int i = blockIdx.x*256 + threadIdx.x;
  if(i >= N_PTS) return;
  int b = batch[i];
  int boff = 0, nb = 1;
  #pragma unroll
  for(int j=0;j<BDIM;j++){
    int nbj = (lengths[j] + TW - 1)/TW;
    if(j <  b) boff += nbj;
    if(j == b) nb = nbj;
  }
  float sc = scores[i];
  int local = (int)(sc * (float)nb);
  if(local > nb-1) local = nb-1;
  if(local < 0) local = 0;
  int g = local + boff;
  gb[i] = g;
  atomicAdd(&hist[g], 1);
}

// ---------------- exclusive scan over MAXB histogram ----------------
__global__ __launch_bounds__(256) void k_scan(const int* __restrict__ hist,
                                              int* __restrict__ start, int* __restrict__ cursor){
  __shared__ int ssum[256];
  const int t = threadIdx.x;
  const int CH = 9;              // 256*9 = 2304 >= 2056
  int loc[CH];
  int s = 0;
  #pragma unroll
  for(int i=0;i<CH;i++){
    int idx = t*CH + i;
    int v = (idx < MAXB) ? hist[idx] : 0;
    loc[i] = s; s += v;
  }
  ssum[t] = s; __syncthreads();
  for(int off=1; off<256; off<<=1){
    int v = (t>=off)? ssum[t-off] : 0;
    __syncthreads();
    ssum[t] += v;
    __syncthreads();
  }
  int ex = ssum[t] - s;          // exclusive prefix of this chunk
  #pragma unroll
  for(int i=0;i<CH;i++){
    int idx = t*CH + i;
    if(idx < MAXB){ int st = ex + loc[i]; start[idx] = st; cursor[idx] = st; }
  }
}

// ---------------- counting-sort scatter ----------------
__global__ __launch_bounds__(256) void k_scatter(const int* __restrict__ gb,
                                                 int* __restrict__ cursor, int* __restrict__ sidx){
  int i = blockIdx.x*256 + threadIdx.x;
  if(i >= N_PTS) return;
  int pos = atomicAdd(&cursor[gb[i]], 1);
  sidx[pos] = i;
}

// ---------------- per-bucket centroid of LN1(feat), load-ahead pipelined ----------------
__global__ __launch_bounds__(256) void k_centroid(const float* __restrict__ feat,
                                                  const int* __restrict__ sidx,
                                                  const int* __restrict__ start,
                                                  const int* __restrict__ hist,
                                                  const float* __restrict__ g1, const float* __restrict__ b1,
                                                  float* __restrict__ cent){
  const int b = blockIdx.x;
  const int cnt = hist[b], st = start[b];
  const int tid = threadIdx.x;
  const int w = tid>>6, lane = tid&63;
  const int c0 = lane*2;
  float g1a = g1[c0], g1b = g1[c0+1];
  float b1a = b1[c0], b1b = b1[c0+1];
  float a0 = 0.f, a1 = 0.f;
  float nx0 = 0.f, nx1 = 0.f;
  int i = w;
  if(i < cnt){
    int p = sidx[st+i];
    const float* fp = feat + (size_t)p*CDIM + c0;
    nx0 = fp[0]; nx1 = fp[1];
  }
  for(; i < cnt; ){
    float x0 = nx0, x1 = nx1;
    int ni = i + 4;
    if(ni < cnt){                                   // prefetch next point under the reduce
      int np = sidx[st+ni];
      const float* fp = feat + (size_t)np*CDIM + c0;
      nx0 = fp[0]; nx1 = fp[1];
    }
    float s = x0+x1, sq = x0*x0 + x1*x1;
    #pragma unroll
    for(int m=1;m<64;m<<=1){ s += __shfl_xor(s,m,64); sq += __shfl_xor(sq,m,64); }
    float mu = s*(1.f/128.f);
    float var = sq*(1.f/128.f) - mu*mu;
    float rs = rsqrtf(var + LN_EPS);
    a0 += (x0-mu)*rs*g1a + b1a;
    a1 += (x1-mu)*rs*g1b + b1b;
    i = ni;
  }
  __shared__ float red[4][128];
  red[w][c0] = a0; red[w][c0+1] = a1;
  __syncthreads();
  if(tid < 128){
    float t = red[0][tid] + red[1][tid] + red[2][tid] + red[3][tid];
    float cf = (float)(cnt > 0 ? cnt : 1);
    cent[(size_t)b*CDIM + tid] = t / cf;
  }
}

// ---------------- centroid projections kc = cent@Wk+bk, vc = cent@Wv+bv ----------------
__global__ __launch_bounds__(128) void k_cgemm(const float* __restrict__ cent,
                                               const float* __restrict__ Wk, const float* __restrict__ bk,
                                               const float* __restrict__ Wv, const float* __restrict__ bv,
                                               float* __restrict__ kc, float* __restrict__ vc){
  const int b = blockIdx.x, t = threadIdx.x;
  __shared__ float sc[128];
  sc[t] = cent[(size_t)b*CDIM + t];
  __syncthreads();
  float ak = bk[t], av = bv[t];
  for(int d=0; d<CDIM; ++d){
    float c = sc[d];
    ak += c * Wk[d*CDIM + t];
    av += c * Wv[d*CDIM + t];
  }
  kc[(size_t)b*CDIM + t] = ak;
  vc[(size_t)b*CDIM + t] = av;
}

// ---------------- pack all 5 fp32 weights into bf16 per-MFMA-B-fragment layout ----------------
__device__ __forceinline__ void pack_one(const float* __restrict__ W, u16* __restrict__ dst,
                                         int NC, int idx){
  int e = idx & 7;
  int l = (idx>>3) & 63;
  int f = idx >> 9;
  int nCT = NC >> 4;
  int cT = f % nCT, kT = f / nCT;
  int k = kT*32 + (l>>4)*8 + e;
  int c = cT*16 + (l&15);
  dst[idx] = f2bf(W[k*NC + c]);
}
__global__ __launch_bounds__(256) void k_packall(const float* __restrict__ Wq, u16* __restrict__ pWq,
                                                 const float* __restrict__ Wg, u16* __restrict__ pWg,
                                                 const float* __restrict__ Wp, u16* __restrict__ pWp,
                                                 const float* __restrict__ W1, u16* __restrict__ pW1,
                                                 const float* __restrict__ W2, u16* __restrict__ pW2){
  int idx = blockIdx.x*256 + threadIdx.x;
  if(idx < 16384){ pack_one(Wq, pWq, CDIM, idx); return; }
  idx -= 16384;
  if(idx < 16384){ pack_one(Wg, pWg, CDIM, idx); return; }
  idx -= 16384;
  if(idx < 16384){ pack_one(Wp, pWp, CDIM, idx); return; }
  idx -= 16384;
  if(idx < 32768){ pack_one(W1, pW1, HID, idx); return; }
  idx -= 32768;
  if(idx < 32768){ pack_one(W2, pW2, CDIM, idx); }
}

// ---------------- attention kernel: LN1 -> Q -> gate -> Wp -> x1 = feat + x_out ----------------
// Split from the R9 mega-kernel: the 6-phase fused chain was latency-bound
// (458us, all pipes <10%, traffic already minimal). Two kernels halve the
// per-wave serial chain; x1 HBM round-trip costs only ~40us. Keeps: acc4[4]
// register cap (no spill at any allocator target), warp-private LDS slabs
// (no __syncthreads), sched_barrier(0) phase walls (keep regalloc sane, R9).
__global__ __attribute__((amdgpu_flat_work_group_size(256, 256)))
void k_attn2(const float* __restrict__ feat,
             const int* __restrict__ gb,
             const float* __restrict__ kc, const float* __restrict__ vc,
             const u16* __restrict__ pWq, const u16* __restrict__ pWg,
             const u16* __restrict__ pWp,
             const float* __restrict__ bq, const float* __restrict__ bg,
             const float* __restrict__ bp,
             const float* __restrict__ g1, const float* __restrict__ b1,
             float* __restrict__ out){
  __shared__ __align__(16) u16 bufA[64*128];   // x_ln -> gate
  __shared__ __align__(16) u16 bufQ[64*128];   // q
  char* A8 = (char*)bufA;
  char* Q8 = (char*)bufQ;
  const int tid = threadIdx.x;
  const int wid = tid>>6, lane = tid&63;
  const int row0 = blockIdx.x*64;

  // ---- Phase A: stage LN1(feat) into bufA (swizzled bf16) ----
  {
    const int cb = (lane&15)*16;
    const f32x8 gv  = *(const f32x8*)(g1 + (lane&15)*8);
    const f32x8 bv8 = *(const f32x8*)(b1 + (lane&15)*8);
    #pragma unroll
    for(int it=0; it<4; ++it){
      int rl = wid*16 + it*4 + (lane>>4);
      const f32x8 f8 = *(const f32x8*)(feat + (size_t)(row0+rl)*CDIM + (lane&15)*8);
      float s=0.f, sq=0.f;
      #pragma unroll
      for(int e=0;e<8;e++){ s += f8[e]; sq += f8[e]*f8[e]; }
      #pragma unroll
      for(int m=1;m<16;m<<=1){ s += __shfl_xor(s,m,64); sq += __shfl_xor(sq,m,64); }
      float mu = s*(1.f/128.f);
      float var = sq*(1.f/128.f) - mu*mu;
      float rs = rsqrtf(var + LN_EPS);
      short8v h;
      #pragma unroll
      for(int e=0;e<8;e++){
        float x = (f8[e]-mu)*rs*gv[e] + bv8[e];
        h[e] = (short)f2bf(x);
      }
      *(short8v*)(A8 + rl*256 + (cb ^ ((rl&7)<<4))) = h;
    }
  }
  __builtin_amdgcn_sched_barrier(0);

  const int arow = wid*16 + (lane&15);
  const int kgrp = (lane>>4);

  short8v af[4];
  f32x4 acc4[4];

  // ---- Phase B: q = x_ln @ Wq + bq -> bufQ (two 4-cT halves) ----
  #pragma unroll
  for(int kT=0;kT<4;kT++)
    af[kT] = *(const short8v*)(A8 + arow*256 + (((kT*64) + kgrp*16) ^ ((arow&7)<<4)));
  #pragma unroll
  for(int h=0;h<2;h++){
    #pragma unroll
    for(int c4=0;c4<4;c4++){
      int cT = h*4 + c4;
      f32x4 a = {0.f,0.f,0.f,0.f};
      #pragma unroll
      for(int kT=0;kT<4;kT++){
        const short8v b8 = *(const short8v*)(pWq + ((size_t)((kT*8+cT)*64 + lane)*8));
        a = __builtin_amdgcn_mfma_f32_16x16x32_bf16(af[kT], b8, a, 0,0,0);
      }
      acc4[c4] = a;
    }
    #pragma unroll
    for(int c4=0;c4<4;c4++){
      int col = (h*4+c4)*16 + (lane&15);
      float bqv = bq[col];
      #pragma unroll
      for(int r=0;r<4;r++){
        int rl = wid*16 + kgrp*4 + r;
        *(u16*)(Q8 + rl*256 + ((col*2) ^ ((rl&7)<<4))) = f2bf(acc4[c4][r] + bqv);
      }
    }
  }
  __builtin_amdgcn_sched_barrier(0);

  const int myb = gb[row0 + arow];

  // ---- Phase C: gate = sigmoid((q*kc*SCALE) @ Wg + bg) -> bufA ----
  #pragma unroll
  for(int kT=0;kT<4;kT++){
    const short8v q8 = *(const short8v*)(Q8 + arow*256 + (((kT*64) + kgrp*16) ^ ((arow&7)<<4)));
    const f32x4 ka = *(const f32x4*)(kc + (size_t)myb*CDIM + kT*32 + kgrp*8);
    const f32x4 kb = *(const f32x4*)(kc + (size_t)myb*CDIM + kT*32 + kgrp*8 + 4);
    short8v a;
    #pragma unroll
    for(int e=0;e<4;e++) a[e]   = (short)f2bf(bf2f((u16)q8[e])   * ka[e] * SCALE_F);
    #pragma unroll
    for(int e=0;e<4;e++) a[e+4] = (short)f2bf(bf2f((u16)q8[e+4]) * kb[e] * SCALE_F);
    af[kT] = a;
  }
  #pragma unroll
  for(int h=0;h<2;h++){
    #pragma unroll
    for(int c4=0;c4<4;c4++){
      int cT = h*4 + c4;
      f32x4 a = {0.f,0.f,0.f,0.f};
      #pragma unroll
      for(int kT=0;kT<4;kT++){
        const short8v b8 = *(const short8v*)(pWg + ((size_t)((kT*8+cT)*64 + lane)*8));
        a = __builtin_amdgcn_mfma_f32_16x16x32_bf16(af[kT], b8, a, 0,0,0);
      }
      acc4[c4] = a;
    }
    #pragma unroll
    for(int c4=0;c4<4;c4++){
      int col = (h*4+c4)*16 + (lane&15);
      float bgv = bg[col];
      #pragma unroll
      for(int r=0;r<4;r++){
        int rl = wid*16 + kgrp*4 + r;
        float x = acc4[c4][r] + bgv;
        float sg = 1.f/(1.f + __expf(-x));
        *(u16*)(A8 + rl*256 + ((col*2) ^ ((rl&7)<<4))) = f2bf(sg);
      }
    }
  }
  __builtin_amdgcn_sched_barrier(0);

  // ---- Phase D: x_out = (gate*vc) @ Wp + bp ; out = x1 = feat + x_out ----
  #pragma unroll
  for(int kT=0;kT<4;kT++){
    const short8v q8 = *(const short8v*)(A8 + arow*256 + (((kT*64) + kgrp*16) ^ ((arow&7)<<4)));
    const f32x4 va = *(const f32x4*)(vc + (size_t)myb*CDIM + kT*32 + kgrp*8);
    const f32x4 vb = *(const f32x4*)(vc + (size_t)myb*CDIM + kT*32 + kgrp*8 + 4);
    short8v a;
    #pragma unroll
    for(int e=0;e<4;e++) a[e]   = (short)f2bf(bf2f((u16)q8[e])   * va[e]);
    #pragma unroll
    for(int e=0;e<4;e++) a[e+4] = (short)f2bf(bf2f((u16)q8[e+4]) * vb[e]);
    af[kT] = a;
  }
  #pragma unroll
  for(int h=0;h<2;h++){
    #pragma unroll
    for(int c4=0;c4<4;c4++){
      int cT = h*4 + c4;
      f32x4 a = {0.f,0.f,0.f,0.f};
      #pragma unroll
      for(int kT=0;kT<4;kT++){
        const short8v b8 = *(const short8v*)(pWp + ((size_t)((kT*8+cT)*64 + lane)*8));
        a = __builtin_amdgcn_mfma_f32_16x16x32_bf16(af[kT], b8, a, 0,0,0);
      }
      acc4[c4] = a;
    }
    #pragma unroll
    for(int c4=0;c4<4;c4++){
      int col = (h*4+c4)*16 + (lane&15);
      float bpv = bp[col];
      #pragma unroll
      for(int r=0;r<4;r++){
        int rl = wid*16 + kgrp*4 + r;
        size_t gi = (size_t)(row0+rl)*CDIM + col;
        out[gi] = feat[gi] + acc4[c4][r] + bpv;
      }
    }
  }
}

// ---------------- FFN kernel: LN2(x1) -> Wf1 -> innerLN+ReLU -> Wf2 -> out = x1 + ... ----------------
__global__ __attribute__((amdgpu_flat_work_group_size(256, 256)))
void k_ffn2(float* __restrict__ xio,
            const u16* __restrict__ pW1, const u16* __restrict__ pW2,
            const float* __restrict__ bias1, const float* __restrict__ gam_f,
            const float* __restrict__ bet_f, const float* __restrict__ bias2,
            const float* __restrict__ g2, const float* __restrict__ b2){
  __shared__ __align__(16) u16 bufH[64*128];   // LN2(x1) -> t[cols 0..127]
  __shared__ __align__(16) u16 bufT[64*128];   // t[cols 128..255]
  char* H8 = (char*)bufH;
  char* T8 = (char*)bufT;
  const int tid = threadIdx.x;
  const int wid = tid>>6, lane = tid&63;
  const int row0 = blockIdx.x*64;

  // ---- Phase S: stage LN2(x1) into bufH ----
  {
    const int cb = (lane&15)*16;
    const f32x8 gv  = *(const f32x8*)(g2 + (lane&15)*8);
    const f32x8 bv8 = *(const f32x8*)(b2 + (lane&15)*8);
    #pragma unroll
    for(int it=0; it<4; ++it){
      int rl = wid*16 + it*4 + (lane>>4);
      const f32x8 f8 = *(const f32x8*)(xio + (size_t)(row0+rl)*CDIM + (lane&15)*8);
      float s=0.f, sq=0.f;
      #pragma unroll
      for(int e=0;e<8;e++){ s += f8[e]; sq += f8[e]*f8[e]; }
      #pragma unroll
      for(int m=1;m<16;m<<=1){ s += __shfl_xor(s,m,64); sq += __shfl_xor(sq,m,64); }
      float mu = s*(1.f/128.f);
      float var = sq*(1.f/128.f) - mu*mu;
      float rs = rsqrtf(var + LN_EPS);
      short8v h;
      #pragma unroll
      for(int e=0;e<8;e++){
        float x = (f8[e]-mu)*rs*gv[e] + bv8[e];
        h[e] = (short)f2bf(x);
      }
      *(short8v*)(H8 + rl*256 + (cb ^ ((rl&7)<<4))) = h;
    }
  }
  __builtin_amdgcn_sched_barrier(0);

  const int arow = wid*16 + (lane&15);
  const int kgrp = (lane>>4);

  short8v af[4];
  f32x4 acc4[4];

  // ---- Phase E: h = LN2(x1) @ Wf1 + bf1, four 4-cT quarters (acc4 cap);
  //      h staged bf16 into bufH (lo cols, dead after af read) / bufT (hi);
  //      then in-place innerLN+ReLU RMW -> t ----
  #pragma unroll
  for(int kT=0;kT<4;kT++)
    af[kT] = *(const short8v*)(H8 + arow*256 + (((kT*64) + kgrp*16) ^ ((arow&7)<<4)));
  float sE[4]  = {0.f,0.f,0.f,0.f};
  float sqE[4] = {0.f,0.f,0.f,0.f};
  #pragma unroll
  for(int q=0;q<4;q++){
    #pragma unroll
    for(int c4=0;c4<4;c4++){
      int cT = q*4 + c4;
      f32x4 a = {0.f,0.f,0.f,0.f};
      #pragma unroll
      for(int kT=0;kT<4;kT++){
        const short8v b8 = *(const short8v*)(pW1 + ((size_t)((kT*16+cT)*64 + lane)*8));
        a = __builtin_amdgcn_mfma_f32_16x16x32_bf16(af[kT], b8, a, 0,0,0);
      }
      acc4[c4] = a;
    }
    #pragma unroll
    for(int c4=0;c4<4;c4++){
      int cT = q*4 + c4;
      int col = cT*16 + (lane&15);
      float bv = bias1[col];
      char* base = (cT<8) ? H8 : T8;
      int cb = (cT<8) ? col*2 : (col-128)*2;
      #pragma unroll
      for(int r=0;r<4;r++){
        int rl = wid*16 + kgrp*4 + r;
        float v = acc4[c4][r] + bv;
        sE[r] += v; sqE[r] += v*v;
        *(u16*)(base + rl*256 + (cb ^ ((rl&7)<<4))) = f2bf(v);
      }
    }
  }
  {
    float muE[4], rsE[4];
    #pragma unroll
    for(int r=0;r<4;r++){
      float s = sE[r], sq = sqE[r];
      #pragma unroll
      for(int m=1;m<16;m<<=1){ s += __shfl_xor(s,m,64); sq += __shfl_xor(sq,m,64); }
      float mu = s*(1.f/256.f);
      float var = sq*(1.f/256.f) - mu*mu;
      muE[r] = mu; rsE[r] = rsqrtf(var + LN_EPS);
    }
    #pragma unroll
    for(int cT=0;cT<16;cT++){
      int col = cT*16 + (lane&15);
      float gm = gam_f[col], bt = bet_f[col];
      char* base = (cT<8) ? H8 : T8;
      int cb = (cT<8) ? col*2 : (col-128)*2;
      #pragma unroll
      for(int r=0;r<4;r++){
        int rl = wid*16 + kgrp*4 + r;
        u16* p = (u16*)(base + rl*256 + (cb ^ ((rl&7)<<4)));
        float hh = bf2f(*p);
        float t = (hh - muE[r])*rsE[r]*gm + bt;
        *p = f2bf(fmaxf(t, 0.f));
      }
    }
  }
  __builtin_amdgcn_sched_barrier(0);

  // ---- Phase F: out = x1 + t @ Wf2 + bf2 (two 4-cT halves; af reloaded per half) ----
  #pragma unroll
  for(int h=0;h<2;h++){
    #pragma unroll
    for(int c4=0;c4<4;c4++) acc4[c4] = (f32x4){0.f,0.f,0.f,0.f};
    #pragma unroll
    for(int kT=0;kT<4;kT++)
      af[kT] = *(const short8v*)(H8 + arow*256 + (((kT*64) + kgrp*16) ^ ((arow&7)<<4)));
    #pragma unroll
    for(int c4=0;c4<4;c4++){
      int cT = h*4 + c4;
      #pragma unroll
      for(int kT=0;kT<4;kT++){
        const short8v b8 = *(const short8v*)(pW2 + ((size_t)((kT*8+cT)*64 + lane)*8));
        acc4[c4] = __builtin_amdgcn_mfma_f32_16x16x32_bf16(af[kT], b8, acc4[c4], 0,0,0);
      }
    }
    #pragma unroll
    for(int kT=0;kT<4;kT++)
      af[kT] = *(const short8v*)(T8 + arow*256 + (((kT*64) + kgrp*16) ^ ((arow&7)<<4)));
    #pragma unroll
    for(int c4=0;c4<4;c4++){
      int cT = h*4 + c4;
      #pragma unroll
      for(int kT=0;kT<4;kT++){
        const short8v b8 = *(const short8v*)(pW2 + ((size_t)(((kT+4)*8+cT)*64 + lane)*8));
        acc4[c4] = __builtin_amdgcn_mfma_f32_16x16x32_bf16(af[kT], b8, acc4[c4], 0,0,0);
      }
    }
    #pragma unroll
    for(int c4=0;c4<4;c4++){
      int col = (h*4+c4)*16 + (lane&15);
      float bv = bias2[col];
      #pragma unroll
      for(int r=0;r<4;r++){
        int rl = wid*16 + kgrp*4 + r;
        size_t gi = (size_t)(row0+rl)*CDIM + col;
        xio[gi] = xio[gi] + acc4[c4][r] + bv;   // xio holds x1
      }
    }
  }
}

// ---------------- host ----------------
extern "C" void kernel_launch(void* const* d_in, const int* in_sizes, int n_in,
                              void* d_out, int out_size, void* d_ws, size_t ws_size,
                              hipStream_t stream){
  const float* feat    = (const float*)d_in[0];
  const int*   batch   = (const int*)d_in[1];
  const int*   lengths = (const int*)d_in[2];
  const float* scores  = (const float*)d_in[3];
  const float* Wq = (const float*)d_in[4];   const float* bq = (const float*)d_in[5];
  const float* Wk = (const float*)d_in[6];   const float* bk = (const float*)d_in[7];
  const float* Wv = (const float*)d_in[8];   const float* bv = (const float*)d_in[9];
  const float* Wg = (const float*)d_in[10];  const float* bg = (const float*)d_in[11];
  const float* Wp = (const float*)d_in[12];  const float* bp = (const float*)d_in[13];
  const float* g1 = (const float*)d_in[14];  const float* b1 = (const float*)d_in[15];
  const float* g2 = (const float*)d_in[16];  const float* b2 = (const float*)d_in[17];
  const float* Wf1 = (const float*)d_in[18]; const float* bf1 = (const float*)d_in[19];
  const float* gf  = (const float*)d_in[20]; const float* bfb = (const float*)d_in[21];
  const float* Wf2 = (const float*)d_in[22]; const float* bf2b = (const float*)d_in[23];

  char* ws = (char*)d_ws;
  size_t off = 0;
  auto alloc = [&](size_t bytes)->void*{
    void* p = ws + off;
    off = (off + bytes + 255) & ~(size_t)255;
    return p;
  };
  int*  gb     = (int*)alloc((size_t)N_PTS*4);
  int*  hist   = (int*)alloc((size_t)MAXB*4);
  int*  start  = (int*)alloc((size_t)MAXB*4);
  int*  cursor = (int*)alloc((size_t)MAXB*4);
  int*  sidx   = (int*)alloc((size_t)N_PTS*4);
  float* cent  = (float*)alloc((size_t)MAXB*CDIM*4);
  float* kc    = (float*)alloc((size_t)MAXB*CDIM*4);
  float* vc    = (float*)alloc((size_t)MAXB*CDIM*4);
  u16* pWq = (u16*)alloc((size_t)CDIM*CDIM*2);
  u16* pWg = (u16*)alloc((size_t)CDIM*CDIM*2);
  u16* pWp = (u16*)alloc((size_t)CDIM*CDIM*2);
  u16* pW1 = (u16*)alloc((size_t)CDIM*HID*2);
  u16* pW2 = (u16*)alloc((size_t)HID*CDIM*2);

  hipMemsetAsync(hist, 0, (size_t)MAXB*4, stream);

  k_bucket<<<N_PTS/256, 256, 0, stream>>>(batch, lengths, scores, gb, hist);
  k_scan<<<1, 256, 0, stream>>>(hist, start, cursor);
  k_scatter<<<N_PTS/256, 256, 0, stream>>>(gb, cursor, sidx);
  k_centroid<<<MAXB, 256, 0, stream>>>(feat, sidx, start, hist, g1, b1, cent);
  k_cgemm<<<MAXB, 128, 0, stream>>>(cent, Wk, bk, Wv, bv, kc, vc);
  k_packall<<<(114688+255)/256, 256, 0, stream>>>(Wq, pWq, Wg, pWg, Wp, pWp, Wf1, pW1, Wf2, pW2);

  k_attn2<<<N_PTS/64, 256, 0, stream>>>(feat, gb, kc, vc, pWq, pWg, pWp,
                                        bq, bg, bp, g1, b1, (float*)d_out);
  k_ffn2<<<N_PTS/64, 256, 0, stream>>>((float*)d_out, pW1, pW2, bf1, gf, bfb, bf2b, g2, b2);
}